// Round 1
// baseline (1088.429 us; speedup 1.0000x reference)
//
#include <hip/hip_runtime.h>
#include <cstdint>

#define NND 5000
#define NE 160000
#define NF 128
#define NH 256
#define NT 10
#define MT 10
#define NC 8
#define NMAT (NND*MT)      // 50000 per template
#define CG_ITERS 5
#define SINK_IT 30

// ---------------- graph prep ----------------

__global__ void k_count(const int* __restrict__ dst, int* __restrict__ cnt) {
    for (int e = blockIdx.x*blockDim.x + threadIdx.x; e < NE; e += gridDim.x*blockDim.x)
        atomicAdd(&cnt[dst[e]], 1);
}

__global__ void k_dinv(const int* __restrict__ cnt, float* __restrict__ dinv) {
    for (int v = blockIdx.x*blockDim.x + threadIdx.x; v < NND; v += gridDim.x*blockDim.x)
        dinv[v] = rsqrtf((float)(cnt[v] + 1));   // +1 self loop; always >= 1
}

__global__ void k_exscan(const int* __restrict__ cnt, int* __restrict__ rp, int n) {
    const int T = 1024;
    int tid = threadIdx.x;
    int C = (n + T - 1) / T;
    int begin = tid * C, end = begin + C; if (end > n) end = n; if (begin > n) begin = n;
    int s = 0;
    for (int i = begin; i < end; i++) s += cnt[i];
    __shared__ int part[1024];
    part[tid] = s; __syncthreads();
    for (int off = 1; off < T; off <<= 1) {
        int v = (tid >= off) ? part[tid - off] : 0;
        __syncthreads();
        part[tid] += v;
        __syncthreads();
    }
    int run = part[tid] - s;   // exclusive
    for (int i = begin; i < end; i++) { rp[i] = run; run += cnt[i]; }
    if (tid == T - 1) rp[n] = part[T - 1];
}

__global__ void k_scatter_dst(const int* __restrict__ src, const int* __restrict__ dst,
                              const int* __restrict__ rp, int* __restrict__ cur,
                              int* __restrict__ csrS, float* __restrict__ csrC,
                              const float* __restrict__ dinv) {
    for (int e = blockIdx.x*blockDim.x + threadIdx.x; e < NE; e += gridDim.x*blockDim.x) {
        int s = src[e], d = dst[e];
        int pos = rp[d] + atomicAdd(&cur[d], 1);
        csrS[pos] = s;
        csrC[pos] = dinv[s] * dinv[d];
    }
}

__global__ void k_dedup(const int* __restrict__ src, const int* __restrict__ dst,
                        unsigned* __restrict__ bitmap, int* __restrict__ cntS,
                        unsigned char* __restrict__ keep) {
    for (int e = blockIdx.x*blockDim.x + threadIdx.x; e < NE; e += gridDim.x*blockDim.x) {
        int s = src[e], d = dst[e];
        int key = s * NND + d;
        unsigned bit = 1u << (key & 31);
        unsigned old = atomicOr(&bitmap[key >> 5], bit);
        if (!(old & bit)) { keep[e] = 1; atomicAdd(&cntS[s], 1); }
        else keep[e] = 0;
    }
}

__global__ void k_scatter_src(const int* __restrict__ src, const int* __restrict__ dst,
                              const unsigned char* __restrict__ keep,
                              const int* __restrict__ rp, int* __restrict__ cur,
                              int* __restrict__ csrD) {
    for (int e = blockIdx.x*blockDim.x + threadIdx.x; e < NE; e += gridDim.x*blockDim.x) {
        if (keep[e]) {
            int s = src[e];
            int pos = rp[s] + atomicAdd(&cur[s], 1);
            csrD[pos] = dst[e];
        }
    }
}

// ---------------- GCN ----------------

__global__ __launch_bounds__(256) void k_gemm(const float* __restrict__ A,
                                              const float* __restrict__ B,
                                              float* __restrict__ C, int M, int N, int K) {
    const int BM = 64, BN = 64, BK = 16;
    __shared__ float As[BK][BM + 1];
    __shared__ float Bs[BK][BN];
    int tid = threadIdx.x;
    int row0 = blockIdx.y * BM, col0 = blockIdx.x * BN;
    int tx = tid % 16, ty = tid / 16;
    float acc[4][4] = {};
    for (int k0 = 0; k0 < K; k0 += BK) {
#pragma unroll
        for (int l = 0; l < 4; l++) {
            int idx = tid + l * 256;
            int r = idx / BK, kk = idx % BK;
            int gr = row0 + r;
            As[kk][r] = (gr < M) ? A[(size_t)gr * K + k0 + kk] : 0.f;
        }
#pragma unroll
        for (int l = 0; l < 4; l++) {
            int idx = tid + l * 256;
            int kk = idx / BN, c = idx % BN;
            Bs[kk][c] = B[(size_t)(k0 + kk) * N + col0 + c];
        }
        __syncthreads();
#pragma unroll
        for (int kk = 0; kk < BK; kk++) {
            float a[4], b[4];
#pragma unroll
            for (int i = 0; i < 4; i++) a[i] = As[kk][ty * 4 + i];
#pragma unroll
            for (int j = 0; j < 4; j++) b[j] = Bs[kk][tx * 4 + j];
#pragma unroll
            for (int i = 0; i < 4; i++)
#pragma unroll
                for (int j = 0; j < 4; j++) acc[i][j] += a[i] * b[j];
        }
        __syncthreads();
    }
#pragma unroll
    for (int i = 0; i < 4; i++) {
        int gr = row0 + ty * 4 + i;
        if (gr < M) {
#pragma unroll
            for (int j = 0; j < 4; j++)
                C[(size_t)gr * N + col0 + tx * 4 + j] = acc[i][j];
        }
    }
}

__global__ void k_aggregate(const float* __restrict__ hin, const float* __restrict__ bias,
                            float* __restrict__ hout, const int* __restrict__ rp,
                            const int* __restrict__ csrS, const float* __restrict__ csrC,
                            const float* __restrict__ dinv, int relu) {
    int v = blockIdx.x;
    int f = threadIdx.x;
    int F = blockDim.x;
    float dv = dinv[v];
    float acc = hin[(size_t)v * F + f] * dv * dv;   // structural self-loop
    int e0 = rp[v], e1 = rp[v + 1];
    for (int e = e0; e < e1; e++)
        acc += hin[(size_t)csrS[e] * F + f] * csrC[e];
    acc += bias[f];
    if (relu) acc = fmaxf(acc, 0.f);
    hout[(size_t)v * F + f] = acc;
}

// ---------------- FGW prep ----------------

__global__ void k_prep_nodes(const int* __restrict__ cntS, const float* __restrict__ h,
                             float* __restrict__ c1row, float* __restrict__ sx) {
    for (int i = blockIdx.x*blockDim.x + threadIdx.x; i < NND; i += gridDim.x*blockDim.x) {
        c1row[i] = (float)cntS[i] * (1.f / NND);
        float s = 0.f;
        for (int f = 0; f < NF; f++) { float v = h[(size_t)i * NF + f]; s += v * v; }
        sx[i] = s;
    }
}

__global__ void k_prep_tpl(const float* __restrict__ tpl, const float* __restrict__ tplF,
                           float* __restrict__ c2row, float* __restrict__ sF) {
    int c = threadIdx.x;
    if (c < NT * MT) {
        int t = c / MT, j = c % MT;
        float s = 0.f;
        for (int k = 0; k < MT; k++) { float v = tpl[t * 100 + j * 10 + k]; s += v * v; }
        c2row[c] = s * (1.f / MT);
        float sf = 0.f;
        for (int f = 0; f < NF; f++) { float v = tplF[(size_t)c * NF + f]; sf += v * v; }
        sF[c] = sf;
    }
}

__global__ void k_M(const float* __restrict__ h, const float* __restrict__ tplF,
                    const float* __restrict__ sx, const float* __restrict__ sF,
                    float* __restrict__ Mout) {
    int i = blockIdx.x;
    __shared__ float hrow[NF];
    hrow[threadIdx.x] = h[(size_t)i * NF + threadIdx.x];
    __syncthreads();
    int c = threadIdx.x;
    if (c < NT * MT) {
        const float* Fc = tplF + (size_t)c * NF;
        float dot = 0.f;
        for (int f = 0; f < NF; f++) dot += hrow[f] * Fc[f];
        int t = c / MT, j = c % MT;
        Mout[(size_t)t * NMAT + (size_t)i * MT + j] = sx[i] + sF[c] - 2.f * dot;
    }
}

__global__ void k_Tinit(float* __restrict__ T) {
    for (int idx = blockIdx.x*blockDim.x + threadIdx.x; idx < NT * NMAT; idx += gridDim.x*blockDim.x)
        T[idx] = 1.f / (float)NMAT;
}

// ---------------- CG iteration ----------------

__global__ __launch_bounds__(256) void k_grad(const float* __restrict__ T, const float* __restrict__ Mm,
                                              const float* __restrict__ c1row, const float* __restrict__ c2row,
                                              const float* __restrict__ tpl,
                                              const int* __restrict__ rpS, const int* __restrict__ csrD,
                                              float* __restrict__ G, unsigned* __restrict__ scaleBits) {
    int t = blockIdx.y;
    int tid = threadIdx.x;
    __shared__ float tC2[100];
    if (tid < 100) tC2[tid] = 2.f * tpl[t * 100 + tid];
    __syncthreads();
    int i = blockIdx.x * 256 + tid;
    float amax = 0.f;
    if (i < NND) {
        const float* Tt = T + (size_t)t * NMAT;
        const float* Mt = Mm + (size_t)t * NMAT;
        float* Gt = G + (size_t)t * NMAT;
        float L[MT];
#pragma unroll
        for (int j = 0; j < MT; j++) L[j] = 0.f;
        int e0 = rpS[i], e1 = rpS[i + 1];
        for (int e = e0; e < e1; e++) {
            int k = csrD[e];
            const float* Tk = Tt + (size_t)k * MT;
#pragma unroll
            for (int j = 0; j < MT; j++) L[j] += Tk[j];
        }
        float c1 = c1row[i];
#pragma unroll
        for (int j = 0; j < MT; j++) {
            float s = 0.f;
#pragma unroll
            for (int k = 0; k < MT; k++) s += L[k] * tC2[j * 10 + k];
            // grad = (1-a)M + 2a*(constC - C1 T (2C2)^T), a=0.5
            float g = 0.5f * Mt[(size_t)i * MT + j] + (c1 + c2row[t * 10 + j] - s);
            Gt[(size_t)i * MT + j] = g;
            amax = fmaxf(amax, fabsf(g));
        }
    }
    __shared__ float red[256];
    red[tid] = amax; __syncthreads();
    for (int off = 128; off > 0; off >>= 1) {
        if (tid < off) red[tid] = fmaxf(red[tid], red[tid + off]);
        __syncthreads();
    }
    if (tid == 0) atomicMax(&scaleBits[t], __float_as_uint(red[0]));
}

// one block per template; scaling-form sinkhorn, K in f32 regs, u/v in f64
__global__ __launch_bounds__(512, 1) void k_sinkhorn(const float* __restrict__ G,
                                                     const float* __restrict__ scale,
                                                     float* __restrict__ T, float step) {
    int t = blockIdx.x;
    int tid = threadIdx.x;
    float sc = scale[t] + 1e-9f;
    float inv = -1.f / (0.02f * sc);
    const float* Gt = G + (size_t)t * NMAT;
    float* Tt = T + (size_t)t * NMAT;

    float Kf[10][10];
    double u[10];
#pragma unroll
    for (int r = 0; r < 10; r++) {
        int i = tid + r * 512;
        u[r] = 1.0;
        if (i < NND) {
#pragma unroll
            for (int j = 0; j < 10; j++) Kf[r][j] = __expf(Gt[(size_t)i * 10 + j] * inv);
        } else {
#pragma unroll
            for (int j = 0; j < 10; j++) Kf[r][j] = 0.f;
        }
    }

    __shared__ double wred[8][10];
    __shared__ double vsh[10];
    double vv[10];
    int lane = tid & 63, wid = tid >> 6;

    for (int it = 0; it < SINK_IT; it++) {
        double S[10];
#pragma unroll
        for (int j = 0; j < 10; j++) S[j] = 0.0;
#pragma unroll
        for (int r = 0; r < 10; r++) {
            double ur = u[r];
#pragma unroll
            for (int j = 0; j < 10; j++) S[j] += (double)Kf[r][j] * ur;
        }
        // wave reduce (64 lanes)
        for (int off = 32; off > 0; off >>= 1) {
#pragma unroll
            for (int j = 0; j < 10; j++) S[j] += __shfl_down(S[j], off);
        }
        if (lane == 0) {
#pragma unroll
            for (int j = 0; j < 10; j++) wred[wid][j] = S[j];
        }
        __syncthreads();
        if (tid < 10) {
            double s = 0.0;
#pragma unroll
            for (int w = 0; w < 8; w++) s += wred[w][tid];
            vsh[tid] = (1.0 / MT) / s;     // v = q / (K^T u)
        }
        __syncthreads();
#pragma unroll
        for (int j = 0; j < 10; j++) vv[j] = vsh[j];
#pragma unroll
        for (int r = 0; r < 10; r++) {
            double R = 0.0;
#pragma unroll
            for (int j = 0; j < 10; j++) R += (double)Kf[r][j] * vv[j];
            if (tid + r * 512 < NND) u[r] = (1.0 / NND) / R;   // u = p / (K v)
        }
    }
    // T update: T += step*(u K v - T)
#pragma unroll
    for (int r = 0; r < 10; r++) {
        int i = tid + r * 512;
        if (i < NND) {
            double ur = u[r];
#pragma unroll
            for (int j = 0; j < 10; j++) {
                double Tn = ur * (double)Kf[r][j] * vv[j];
                float Told = Tt[(size_t)i * 10 + j];
                Tt[(size_t)i * 10 + j] = Told + step * ((float)Tn - Told);
            }
        }
    }
}

// ---------------- final distance + head ----------------

__global__ __launch_bounds__(256) void k_final(const float* __restrict__ T, const float* __restrict__ Mm,
                                               const float* __restrict__ c1row, const float* __restrict__ c2row,
                                               const float* __restrict__ tpl,
                                               const int* __restrict__ rpS, const int* __restrict__ csrD,
                                               double* __restrict__ dd) {
    int t = blockIdx.y;
    int tid = threadIdx.x;
    __shared__ float tC2[100];
    if (tid < 100) tC2[tid] = 2.f * tpl[t * 100 + tid];
    __syncthreads();
    int i = blockIdx.x * 256 + tid;
    double msum = 0.0, tsum = 0.0;
    if (i < NND) {
        const float* Tt = T + (size_t)t * NMAT;
        const float* Mt = Mm + (size_t)t * NMAT;
        float L[MT];
#pragma unroll
        for (int j = 0; j < MT; j++) L[j] = 0.f;
        int e0 = rpS[i], e1 = rpS[i + 1];
        for (int e = e0; e < e1; e++) {
            int k = csrD[e];
            const float* Tk = Tt + (size_t)k * MT;
#pragma unroll
            for (int j = 0; j < MT; j++) L[j] += Tk[j];
        }
        float c1 = c1row[i];
#pragma unroll
        for (int j = 0; j < MT; j++) {
            float s = 0.f;
#pragma unroll
            for (int k = 0; k < MT; k++) s += L[k] * tC2[j * 10 + k];
            float ts = c1 + c2row[t * 10 + j] - s;
            float Tv = Tt[(size_t)i * MT + j];
            msum += (double)(Mt[(size_t)i * MT + j] * Tv);
            tsum += (double)(ts * Tv);
        }
    }
    __shared__ double r1[256], r2[256];
    r1[tid] = msum; r2[tid] = tsum; __syncthreads();
    for (int off = 128; off > 0; off >>= 1) {
        if (tid < off) { r1[tid] += r1[tid + off]; r2[tid] += r2[tid + off]; }
        __syncthreads();
    }
    if (tid == 0) { atomicAdd(&dd[t * 2], r1[0]); atomicAdd(&dd[t * 2 + 1], r2[0]); }
}

__global__ void k_out(const double* __restrict__ dd, const float* __restrict__ Wlin,
                      const float* __restrict__ blin, float* __restrict__ out) {
    int tid = threadIdx.x;
    __shared__ float ds[NT];
    if (tid < NT) ds[tid] = 0.5f * (float)(dd[2 * tid] + dd[2 * tid + 1]);
    __syncthreads();
    if (tid < NC) {
        float o = blin[tid];
#pragma unroll
        for (int t = 0; t < NT; t++) o += ds[t] * Wlin[t * NC + tid];
        out[tid] = o;
    }
}

// ---------------- host ----------------

extern "C" void kernel_launch(void* const* d_in, const int* in_sizes, int n_in,
                              void* d_out, int out_size, void* d_ws, size_t ws_size,
                              hipStream_t stream) {
    const float* x    = (const float*)d_in[0];
    const int*   ei   = (const int*)d_in[1];
    const int*   src  = ei;
    const int*   dst  = ei + NE;
    const float* W1   = (const float*)d_in[2];
    const float* b1   = (const float*)d_in[3];
    const float* W2   = (const float*)d_in[4];
    const float* b2   = (const float*)d_in[5];
    const float* tpl  = (const float*)d_in[6];
    const float* tplF = (const float*)d_in[7];
    const float* Wlin = (const float*)d_in[8];
    const float* blin = (const float*)d_in[9];
    float* out = (float*)d_out;

    char* w = (char*)d_ws;
    size_t off = 0;
    auto alloc = [&](size_t b) -> char* {
        off = (off + 255) & ~(size_t)255;
        char* p = w + off; off += b; return p;
    };
    float* bufA = (float*)alloc((size_t)NND * NH * 4);
    float* bufB = (float*)alloc((size_t)NND * NH * 4);
    float* bufH = (float*)alloc((size_t)NND * NF * 4);
    float* Mm   = (float*)alloc((size_t)NT * NMAT * 4);
    float* T    = (float*)alloc((size_t)NT * NMAT * 4);
    float* G    = (float*)alloc((size_t)NT * NMAT * 4);
    // --- zero group (one memset) ---
    int* cntD = (int*)alloc((size_t)NND * 4);
    int* cntS = (int*)alloc((size_t)NND * 4);
    int* cur1 = (int*)alloc((size_t)NND * 4);
    int* cur2 = (int*)alloc((size_t)NND * 4);
    double* dd = (double*)alloc((size_t)NT * 2 * 8);
    char* zend = w + off;
    // --- rest ---
    unsigned* scaleBits = (unsigned*)alloc((size_t)NT * 4);
    unsigned* bitmap = (unsigned*)alloc((size_t)781250 * 4);
    int* rpD  = (int*)alloc((size_t)(NND + 1) * 4);
    int* rpS  = (int*)alloc((size_t)(NND + 1) * 4);
    int* csrS = (int*)alloc((size_t)NE * 4);
    float* csrC = (float*)alloc((size_t)NE * 4);
    int* csrD2 = (int*)alloc((size_t)NE * 4);
    unsigned char* keep = (unsigned char*)alloc((size_t)NE);
    float* dinv  = (float*)alloc((size_t)NND * 4);
    float* c1row = (float*)alloc((size_t)NND * 4);
    float* sx    = (float*)alloc((size_t)NND * 4);
    float* sF    = (float*)alloc((size_t)100 * 4);
    float* c2row = (float*)alloc((size_t)100 * 4);

    hipMemsetAsync(cntD, 0, (size_t)(zend - (char*)cntD), stream);
    hipMemsetAsync(bitmap, 0, (size_t)781250 * 4, stream);

    // graph prep
    k_count<<<625, 256, 0, stream>>>(dst, cntD);
    k_dinv<<<20, 256, 0, stream>>>(cntD, dinv);
    k_exscan<<<1, 1024, 0, stream>>>(cntD, rpD, NND);
    k_scatter_dst<<<625, 256, 0, stream>>>(src, dst, rpD, cur1, csrS, csrC, dinv);

    // GCN
    k_gemm<<<dim3(NH / 64, (NND + 63) / 64), 256, 0, stream>>>(x, W1, bufA, NND, NH, NF);
    k_aggregate<<<NND, NH, 0, stream>>>(bufA, b1, bufB, rpD, csrS, csrC, dinv, 1);
    k_gemm<<<dim3(NF / 64, (NND + 63) / 64), 256, 0, stream>>>(bufB, W2, bufA, NND, NF, NH);
    k_aggregate<<<NND, NF, 0, stream>>>(bufA, b2, bufH, rpD, csrS, csrC, dinv, 0);

    // dedup adjacency + CSR by src
    k_dedup<<<625, 256, 0, stream>>>(src, dst, bitmap, cntS, keep);
    k_exscan<<<1, 1024, 0, stream>>>(cntS, rpS, NND);
    k_scatter_src<<<625, 256, 0, stream>>>(src, dst, keep, rpS, cur2, csrD2);

    // FGW prep
    k_prep_nodes<<<20, 256, 0, stream>>>(cntS, bufH, c1row, sx);
    k_prep_tpl<<<1, 128, 0, stream>>>(tpl, tplF, c2row, sF);
    k_M<<<NND, 128, 0, stream>>>(bufH, tplF, sx, sF, Mm);
    k_Tinit<<<1954, 256, 0, stream>>>(T);

    // conditional gradient loop
    for (int t = 0; t < CG_ITERS; t++) {
        hipMemsetAsync(scaleBits, 0, NT * 4, stream);
        k_grad<<<dim3(20, NT), 256, 0, stream>>>(T, Mm, c1row, c2row, tpl, rpS, csrD2, G, scaleBits);
        float step = 2.f / (float)(t + 2);
        k_sinkhorn<<<NT, 512, 0, stream>>>(G, (const float*)scaleBits, T, step);
    }

    // final distances + linear head
    k_final<<<dim3(20, NT), 256, 0, stream>>>(T, Mm, c1row, c2row, tpl, rpS, csrD2, dd);
    k_out<<<1, 64, 0, stream>>>(dd, Wlin, blin, out);
}